// Round 1
// baseline (730.485 us; speedup 1.0000x reference)
//
#include <hip/hip_runtime.h>
#include <math.h>

namespace {

constexpr int B_ = 8, C_ = 256, H_ = 128, W_ = 192;
constexpr int R_ = 4, ND = 9;                 // 2R+1 displacements per axis
constexpr int TH = 8;                          // h rows per block
constexpr int TW = 64;                         // w cols per block
constexpr int WPT = 8;                         // w positions per thread
constexpr int WG = TW / WPT;                   // 8 w-groups
constexpr int NHW = TH * WG;                   // 64
constexpr int NTHREADS = NHW * ND;             // 576 (9 waves)
constexpr int KC = 4;                          // channels per LDS chunk
constexpr int F2ROWS = TH + 2 * R_;            // 16
constexpr int F2W = 80;                        // staged f2 width (w0-8 .. w0+72)
constexpr int F2STRIDE = 84;                   // pad: 84 mod 32 = 20 -> banks spread
constexpr int F1SLOTS = TH * TW / 4;           // 128 float4 slots per channel
constexpr int F2SLOTS = F2ROWS * (F2W / 4);    // 320 float4 slots per channel
constexpr int NSLOTS = F1SLOTS + F2SLOTS;      // 448

__global__ __launch_bounds__(NTHREADS)
void local_corr_kernel(const float* __restrict__ f1g,
                       const float* __restrict__ f2g,
                       float* __restrict__ outg)
{
    __shared__ float s_f1[KC][TH][TW];          // 8 KB
    __shared__ float s_f2[KC][F2ROWS][F2STRIDE];// 21 KB

    const int tid = threadIdx.x;
    const int w0  = blockIdx.x * TW;
    const int h0  = blockIdx.y * TH;
    const int b   = blockIdx.z;

    // compute-role decomposition: 9 consecutive tids share one (h,wgrp) -> f1 broadcast
    const int dyi  = tid % ND;        // 0..8  (dy = dyi - 4)
    const int hw   = tid / ND;        // 0..63
    const int hloc = hw >> 3;         // 0..7
    const int wl   = (hw & 7) * WPT;  // 0,8,...,56

    // staging-role decomposition: fixed spatial position per thread across all c,
    // so squared-norm sums accumulate in registers.
    const bool isStage = tid < NSLOTS;
    const bool isF1    = tid < F1SLOTS;
    int st_row = 0, st_col = 0;
    int gh = 0, gx0 = 0;
    bool fast = false;
    const float* st_base = nullptr;
    if (isStage) {
        if (isF1) {
            st_row = tid >> 4;             // 0..7
            st_col = (tid & 15) * 4;       // 0..60
            gh = h0 + st_row;
            gx0 = w0 + st_col;
            st_base = f1g;
            fast = true;                   // f1 tile always in-bounds
        } else {
            const int s2 = tid - F1SLOTS;  // 0..319
            st_row = s2 / 20;              // 0..15
            st_col = (s2 % 20) * 4;        // 0..76
            gh = h0 - R_ + st_row;
            gx0 = w0 - 8 + st_col;
            st_base = f2g;
            fast = (gh >= 0) && (gh < H_) && (gx0 >= 0) && (gx0 + 3 < W_);
        }
    }

    float acc[WPT][ND];
#pragma unroll
    for (int i = 0; i < WPT; ++i)
#pragma unroll
        for (int j = 0; j < ND; ++j) acc[i][j] = 0.0f;

    float s4x = 0.f, s4y = 0.f, s4z = 0.f, s4w = 0.f;  // per-position sq-sums

    for (int c0 = 0; c0 < C_; c0 += KC) {
        if (isStage) {
#pragma unroll
            for (int cc = 0; cc < KC; ++cc) {
                const int c = c0 + cc;
                const size_t plane = ((size_t)b * C_ + c) * H_;
                float4 v;
                if (fast) {
                    v = *reinterpret_cast<const float4*>(
                        st_base + (plane + gh) * W_ + gx0);
                } else {
                    const bool rok = (gh >= 0) && (gh < H_);
                    const float* rp = st_base + (plane + (rok ? gh : 0)) * W_;
                    v.x = (rok && gx0 + 0 >= 0 && gx0 + 0 < W_) ? rp[gx0 + 0] : 0.f;
                    v.y = (rok && gx0 + 1 >= 0 && gx0 + 1 < W_) ? rp[gx0 + 1] : 0.f;
                    v.z = (rok && gx0 + 2 >= 0 && gx0 + 2 < W_) ? rp[gx0 + 2] : 0.f;
                    v.w = (rok && gx0 + 3 >= 0 && gx0 + 3 < W_) ? rp[gx0 + 3] : 0.f;
                }
                s4x += v.x * v.x; s4y += v.y * v.y;
                s4z += v.z * v.z; s4w += v.w * v.w;
                if (isF1) {
                    *reinterpret_cast<float4*>(&s_f1[cc][st_row][st_col]) = v;
                } else {
                    *reinterpret_cast<float4*>(&s_f2[cc][st_row][st_col]) = v;
                }
            }
        }
        __syncthreads();

#pragma unroll
        for (int cc = 0; cc < KC; ++cc) {
            float a[WPT];
            *reinterpret_cast<float4*>(&a[0]) =
                *reinterpret_cast<const float4*>(&s_f1[cc][hloc][wl]);
            *reinterpret_cast<float4*>(&a[4]) =
                *reinterpret_cast<const float4*>(&s_f1[cc][hloc][wl + 4]);
            float v[16];
            const float* frow = &s_f2[cc][hloc + dyi][wl + 4];
#pragma unroll
            for (int k = 0; k < 4; ++k)
                *reinterpret_cast<float4*>(&v[k * 4]) =
                    *reinterpret_cast<const float4*>(&frow[k * 4]);
#pragma unroll
            for (int wi = 0; wi < WPT; ++wi)
#pragma unroll
                for (int dxi = 0; dxi < ND; ++dxi)
                    acc[wi][dxi] += a[wi] * v[wi + dxi];
        }
        __syncthreads();
    }

    // write per-position squared norms into the (now free) c=0 LDS buffers
    if (isStage) {
        float4 s = make_float4(s4x, s4y, s4z, s4w);
        if (isF1) {
            *reinterpret_cast<float4*>(&s_f1[0][st_row][st_col]) = s;
        } else {
            *reinterpret_cast<float4*>(&s_f2[0][st_row][st_col]) = s;
        }
    }
    __syncthreads();

    // epilogue: out = raw_dot * inv||f1|| * inv||f2||  (matches x/max(||x||,eps))
    const int h = h0 + hloc;
    float inv1[WPT];
#pragma unroll
    for (int wi = 0; wi < WPT; ++wi) {
        const float n = sqrtf(s_f1[0][hloc][wl + wi]);
        inv1[wi] = 1.0f / fmaxf(n, 1e-12f);
    }
    float inv2[16];
    const float* nrow = &s_f2[0][hloc + dyi][wl + 4];
#pragma unroll
    for (int k = 0; k < 16; ++k) {
        const float n = sqrtf(nrow[k]);
        inv2[k] = 1.0f / fmaxf(n, 1e-12f);
    }

#pragma unroll
    for (int dxi = 0; dxi < ND; ++dxi) {
        const int d = dyi * ND + dxi;
        float o[WPT];
#pragma unroll
        for (int wi = 0; wi < WPT; ++wi)
            o[wi] = acc[wi][dxi] * inv1[wi] * inv2[wi + dxi];
        float* op = outg + (((size_t)b * (ND * ND) + d) * H_ + h) * W_ + w0 + wl;
        *reinterpret_cast<float4*>(&op[0]) = make_float4(o[0], o[1], o[2], o[3]);
        *reinterpret_cast<float4*>(&op[4]) = make_float4(o[4], o[5], o[6], o[7]);
    }
}

} // namespace

extern "C" void kernel_launch(void* const* d_in, const int* in_sizes, int n_in,
                              void* d_out, int out_size, void* d_ws, size_t ws_size,
                              hipStream_t stream)
{
    (void)in_sizes; (void)n_in; (void)d_ws; (void)ws_size; (void)out_size;
    const float* f1 = (const float*)d_in[0];
    const float* f2 = (const float*)d_in[1];
    float* out = (float*)d_out;

    dim3 grid(W_ / TW, H_ / TH, B_);   // (3, 16, 8) = 384 blocks
    dim3 block(NTHREADS);              // 576 threads = 9 waves
    local_corr_kernel<<<grid, block, 0, stream>>>(f1, f2, out);
}